// Round 4
// baseline (902.834 us; speedup 1.0000x reference)
//
#include <hip/hip_runtime.h>

// GCN autoencoder: N=100000 nodes, E=1600000 edges, 512 -> 64 -> 512.
// R2: dst-CSR gather instead of atomic scatter.
// R3: gemm1 retiled 128-row/24.5KB LDS + register prefetch.
// R4: rank trick (atomic-free fill), hist fused with gemm1 (block split).
// R5: FAILED - XCD-local workgroup-scope histogram crashed (rank[] holes ->
//     OOB scatter). Two unproven assumptions (XCD block coverage, WG-scope
//     L2 atomic coherence). Reverted.
// R6 (this round): histogram back to proven device-scope atomics (R1 form);
//     KEEP gather2+gemm2 fusion from R5 for isolated attribution:
//     gathers 64 rows into LDS then 4 col-tiles of W2 -- kills the agg2
//     HBM round trip and old gemm2's 4x A re-read.
// Pipeline: memset -> gemm1+hist -> scan1 -> scan2 -> scan3+norm ->
//           fill(no atomics) -> gather1 -> gather_gemm2.

// ---------------- fused GEMM1 + edge histogram ----------------
// blocks [0, gemmBlocks): C[M x 64] = A[M x 512] @ B[512 x 64]
// blocks [gemmBlocks, ...): degO[src]++ (float), rank[e] = cnt[dst]++
__launch_bounds__(256)
__global__ void gemm1_hist_kernel(const float* __restrict__ A, const float* __restrict__ B,
                                  float* __restrict__ C, int M,
                                  const int* __restrict__ src, const int* __restrict__ dst,
                                  float* __restrict__ degO, int* __restrict__ cnt,
                                  int* __restrict__ rank, int E, int gemmBlocks) {
    __shared__ __align__(16) float As[32][132];   // k-major, 128 rows + pad
    __shared__ __align__(16) float Bs[32][64];

    if ((int)blockIdx.x >= gemmBlocks) {
        // -------- histogram path (no barriers; device-scope atomics) ------
        int hb = blockIdx.x - gemmBlocks;
        int histThreads = (gridDim.x - gemmBlocks) * 256;
        for (int e = hb * 256 + threadIdx.x; e < E; e += histThreads) {
            int s = src[e];
            int d = dst[e];
            atomicAdd(&degO[s], 1.0f);            // fire-and-forget
            rank[e] = atomicAdd(&cnt[d], 1);      // rank within dst row
        }
        return;
    }

    // -------- gemm path --------
    const int tid = threadIdx.x;
    const int txn = tid & 7;       // 8 col-groups of 8 cols
    const int tym = tid >> 3;      // 32 row-groups of 4 rows
    const int rowBase = blockIdx.x * 128;

    float4 ra[4];  // staged A: 4 x float4 per thread (128x32 tile)
    float4 rb[2];  // staged B: 2 x float4 per thread (32x64 tile)

    auto gload = [&](int k0) {
#pragma unroll
        for (int p = 0; p < 4; ++p) {
            int idx = p * 256 + tid;
            int r  = idx >> 3;
            int kv = (idx & 7) * 4;
            int gr = rowBase + r;
            ra[p] = make_float4(0.f, 0.f, 0.f, 0.f);
            if (gr < M) ra[p] = *(const float4*)(A + (size_t)gr * 512 + k0 + kv);
        }
#pragma unroll
        for (int p = 0; p < 2; ++p) {
            int idx = p * 256 + tid;
            int kr = idx >> 4;
            int nv = (idx & 15) * 4;
            rb[p] = *(const float4*)(B + (size_t)(k0 + kr) * 64 + nv);
        }
    };

    float acc[4][8];
#pragma unroll
    for (int i = 0; i < 4; ++i)
#pragma unroll
        for (int j = 0; j < 8; ++j) acc[i][j] = 0.0f;

    gload(0);
    for (int k0 = 0; k0 < 512; k0 += 32) {
#pragma unroll
        for (int p = 0; p < 4; ++p) {
            int idx = p * 256 + tid;
            int r  = idx >> 3;
            int kv = (idx & 7) * 4;
            As[kv + 0][r] = ra[p].x; As[kv + 1][r] = ra[p].y;
            As[kv + 2][r] = ra[p].z; As[kv + 3][r] = ra[p].w;
        }
#pragma unroll
        for (int p = 0; p < 2; ++p) {
            int idx = p * 256 + tid;
            int kr = idx >> 4;
            int nv = (idx & 15) * 4;
            *(float4*)&Bs[kr][nv] = rb[p];
        }
        __syncthreads();
        if (k0 + 32 < 512) gload(k0 + 32);  // prefetch next tile under compute

#pragma unroll 8
        for (int k = 0; k < 32; ++k) {
            float a[4], b[8];
            *(float4*)&a[0] = *(const float4*)&As[k][tym * 4];
            *(float4*)&b[0] = *(const float4*)&Bs[k][txn * 8];
            *(float4*)&b[4] = *(const float4*)&Bs[k][txn * 8 + 4];
#pragma unroll
            for (int i = 0; i < 4; ++i)
#pragma unroll
                for (int j = 0; j < 8; ++j)
                    acc[i][j] = fmaf(a[i], b[j], acc[i][j]);
        }
        __syncthreads();
    }

#pragma unroll
    for (int i = 0; i < 4; ++i) {
        int gr = rowBase + tym * 4 + i;
        if (gr < M) {
            *(float4*)(C + (size_t)gr * 64 + txn * 8) =
                make_float4(acc[i][0], acc[i][1], acc[i][2], acc[i][3]);
            *(float4*)(C + (size_t)gr * 64 + txn * 8 + 4) =
                make_float4(acc[i][4], acc[i][5], acc[i][6], acc[i][7]);
        }
    }
}

// ---------------- exclusive scan of cnt -> rowptr (3-phase) ----------------
__global__ void scan_pass1(const int* __restrict__ cnt, int* __restrict__ rowptr,
                           int* __restrict__ bsum, int n) {
    __shared__ int tmp[256];
    int tid = threadIdx.x;
    int i = blockIdx.x * 256 + tid;
    int v = (i < n) ? cnt[i] : 0;
    tmp[tid] = v;
    __syncthreads();
    for (int off = 1; off < 256; off <<= 1) {
        int t = (tid >= off) ? tmp[tid - off] : 0;
        __syncthreads();
        tmp[tid] += t;
        __syncthreads();
    }
    if (i < n) rowptr[i] = tmp[tid] - v;  // block-local exclusive
    if (tid == 255) bsum[blockIdx.x] = tmp[255];
}

__global__ void scan_pass2(int* __restrict__ bsum, int nb) {
    __shared__ int tmp[512];
    int tid = threadIdx.x;
    int v = (tid < nb) ? bsum[tid] : 0;
    tmp[tid] = v;
    __syncthreads();
    for (int off = 1; off < 512; off <<= 1) {
        int t = (tid >= off) ? tmp[tid - off] : 0;
        __syncthreads();
        tmp[tid] += t;
        __syncthreads();
    }
    if (tid < nb) bsum[tid] = tmp[tid] - v;  // exclusive block offsets
}

// scan finalize + norm computation fused (ns holds float degO counts)
__global__ void scan3_norm(int* __restrict__ rowptr, const int* __restrict__ bsum,
                           float* __restrict__ ns, float* __restrict__ nd,
                           float* __restrict__ scale2, const int* __restrict__ cnt,
                           int n, int E) {
    int i = blockIdx.x * 256 + threadIdx.x;
    if (i < n) {
        rowptr[i] += bsum[blockIdx.x];
        float a = rsqrtf(fmaxf(ns[i], 1.0f));
        float b = rsqrtf(fmaxf((float)cnt[i], 1.0f));
        ns[i] = a; nd[i] = b; scale2[i] = a * b;
    }
    if (i == 0) rowptr[n] = E;
}

// ---------------- CSR fill: atomic-free via precomputed rank ----------------
__global__ void fill_csr(const int* __restrict__ src, const int* __restrict__ dst,
                         const int* __restrict__ rank, const int* __restrict__ rowptr,
                         int* __restrict__ csr, int E) {
    int e = blockIdx.x * blockDim.x + threadIdx.x;
    if (e < E) {
        csr[rowptr[dst[e]] + rank[e]] = src[e];
    }
}

// ---------------- gather aggregation: one wave per node, lane = feature ----------------
template <bool RELU>
__global__ void gather_kernel(const float* __restrict__ x, const int* __restrict__ rowptr,
                              const int* __restrict__ csr, const float* __restrict__ scale,
                              float* __restrict__ out, int N) {
    int node = blockIdx.x * 4 + (threadIdx.x >> 6);
    if (node >= N) return;
    int lane = threadIdx.x & 63;
    int beg = rowptr[node], end = rowptr[node + 1];
    float acc = 0.0f;
    int i = beg;
    for (; i + 1 < end; i += 2) {  // 2x unroll for MLP
        int s0 = csr[i], s1 = csr[i + 1];
        float sc0 = scale[s0], sc1 = scale[s1];
        float v0 = x[(size_t)s0 * 64 + lane];
        float v1 = x[(size_t)s1 * 64 + lane];
        if (RELU) { v0 = fmaxf(v0, 0.0f); v1 = fmaxf(v1, 0.0f); }
        acc = fmaf(v0, sc0, acc);
        acc = fmaf(v1, sc1, acc);
    }
    if (i < end) {
        int s = csr[i];
        float v = x[(size_t)s * 64 + lane];
        if (RELU) v = fmaxf(v, 0.0f);
        acc = fmaf(v, scale[s], acc);
    }
    out[(size_t)node * 64 + lane] = acc;
}

// ---------------- fused gather2 + GEMM2 ----------------
// Per block: gather 64 output rows (relu + scale2 at source, nd at dest)
// into As[64][68], then C[64 x 512] = As^T @ W2 via 4 col-tiles of 128.
__launch_bounds__(256)
__global__ void gather_gemm2_kernel(const float* __restrict__ agg1,
                                    const int* __restrict__ rowptr,
                                    const int* __restrict__ csr,
                                    const float* __restrict__ scale2,
                                    const float* __restrict__ nd,
                                    const float* __restrict__ B,
                                    float* __restrict__ C, int N) {
    __shared__ __align__(16) float As[64][68];    // [feature k][row]
    __shared__ __align__(16) float Bs[64][132];   // [k][col-tile 128 + pad]
    const int tid  = threadIdx.x;
    const int lane = tid & 63;
    const int wave = tid >> 6;
    const int rowBase = blockIdx.x * 64;

    // gather phase: each wave fills 16 rows
    for (int j = 0; j < 16; ++j) {
        int rloc = wave * 16 + j;
        int gr = rowBase + rloc;
        float acc = 0.0f;
        if (gr < N) {
            int beg = rowptr[gr], end = rowptr[gr + 1];
            int i = beg;
            for (; i + 1 < end; i += 2) {
                int s0 = csr[i], s1 = csr[i + 1];
                float v0 = fmaxf(agg1[(size_t)s0 * 64 + lane], 0.0f);
                float v1 = fmaxf(agg1[(size_t)s1 * 64 + lane], 0.0f);
                acc = fmaf(v0, scale2[s0], acc);
                acc = fmaf(v1, scale2[s1], acc);
            }
            if (i < end) {
                int s = csr[i];
                acc = fmaf(fmaxf(agg1[(size_t)s * 64 + lane], 0.0f), scale2[s], acc);
            }
            acc *= nd[gr];
        }
        As[lane][rloc] = acc;
    }
    __syncthreads();

    // gemm phase: 4 column tiles of 128
    const int txn = tid & 15;
    const int tym = tid >> 4;
    for (int ct = 0; ct < 4; ++ct) {
        const int colBase = ct * 128;
#pragma unroll
        for (int p = 0; p < 8; ++p) {
            int idx = p * 256 + tid;
            int kr = idx >> 5;
            int nv = (idx & 31) * 4;
            *(float4*)&Bs[kr][nv] = *(const float4*)(B + (size_t)kr * 512 + colBase + nv);
        }
        __syncthreads();

        float acc2[4][8];
#pragma unroll
        for (int i = 0; i < 4; ++i)
#pragma unroll
            for (int j = 0; j < 8; ++j) acc2[i][j] = 0.0f;

#pragma unroll 4
        for (int k = 0; k < 64; ++k) {
            float a[4], b[8];
            *(float4*)&a[0] = *(const float4*)&As[k][tym * 4];
            *(float4*)&b[0] = *(const float4*)&Bs[k][txn * 4];
            *(float4*)&b[4] = *(const float4*)&Bs[k][64 + txn * 4];
#pragma unroll
            for (int i = 0; i < 4; ++i)
#pragma unroll
                for (int j = 0; j < 8; ++j)
                    acc2[i][j] = fmaf(a[i], b[j], acc2[i][j]);
        }

#pragma unroll
        for (int i = 0; i < 4; ++i) {
            int gr = rowBase + tym * 4 + i;
            if (gr < N) {
                *(float4*)(C + (size_t)gr * 512 + colBase + txn * 4) =
                    make_float4(acc2[i][0], acc2[i][1], acc2[i][2], acc2[i][3]);
                *(float4*)(C + (size_t)gr * 512 + colBase + 64 + txn * 4) =
                    make_float4(acc2[i][4], acc2[i][5], acc2[i][6], acc2[i][7]);
            }
        }
        __syncthreads();
    }
}

extern "C" void kernel_launch(void* const* d_in, const int* in_sizes, int n_in,
                              void* d_out, int out_size, void* d_ws, size_t ws_size,
                              hipStream_t stream) {
    const float* feat = (const float*)d_in[0];
    const int*   src  = (const int*)d_in[1];
    const int*   dst  = (const int*)d_in[2];
    const float* W1   = (const float*)d_in[3];
    const float* W2   = (const float*)d_in[4];
    const int N = in_sizes[0] / 512;  // 100000
    const int E = in_sizes[1];        // 1600000
    float* out = (float*)d_out;

    // workspace layout
    float* ns     = (float*)d_ws;            // [N] (degO counts, then rsqrt)
    float* nd     = ns + N;                  // [N]
    float* scale2 = nd + N;                  // [N] = ns*nd
    int*   cnt    = (int*)(scale2 + N);      // [N] in-degree
    int*   rowptr = cnt + N;                 // [N+1]
    int*   bsum   = rowptr + (N + 1);        // [512]
    int*   csr    = bsum + 512;              // [E]
    float* buf1   = (float*)(((unsigned long long)(csr + E) + 15ull) & ~15ull); // [64N]
    float* agg1   = buf1 + (size_t)64 * N;   // [64N]
    int*   rank   = (int*)agg1;              // [E] aliases agg1 (dead until gather1)

    hipMemsetAsync(ns, 0, (size_t)N * sizeof(float), stream);
    hipMemsetAsync(cnt, 0, (size_t)N * sizeof(int), stream);

    // h1 = feat @ W1, concurrently: degree histograms + rank capture
    const int gemmBlocks = (N + 127) / 128;   // 782
    const int histBlocks = 512;
    gemm1_hist_kernel<<<gemmBlocks + histBlocks, 256, 0, stream>>>(
        feat, W1, buf1, N, src, dst, ns, cnt, rank, E, gemmBlocks);

    const int nb = (N + 255) / 256;  // 391 <= 512
    scan_pass1<<<nb, 256, 0, stream>>>(cnt, rowptr, bsum, N);
    scan_pass2<<<1, 512, 0, stream>>>(bsum, nb);
    scan3_norm<<<nb, 256, 0, stream>>>(rowptr, bsum, ns, nd, scale2, cnt, N, E);

    fill_csr<<<(E + 255) / 256, 256, 0, stream>>>(src, dst, rank, rowptr, csr, E);

    // agg1[d] = sum h1[s]*ns[s]   (rank is dead from here on)
    gather_kernel<false><<<(N + 3) / 4, 256, 0, stream>>>(buf1, rowptr, csr, ns, agg1, N);

    // out[d] = (nd[d] * sum relu(agg1[s])*scale2[s]) @ W2, fused
    gather_gemm2_kernel<<<(N + 63) / 64, 256, 0, stream>>>(
        agg1, rowptr, csr, scale2, nd, W2, out, N);
}

// Round 5
// 714.318 us; speedup vs baseline: 1.2639x; 1.2639x over previous
//
#include <hip/hip_runtime.h>

// GCN autoencoder: N=100000 nodes, E=1600000 edges, 512 -> 64 -> 512.
// R2: dst-CSR gather instead of atomic scatter.
// R3: gemm1 retiled 128-row/24.5KB LDS + register prefetch.
// R4: rank trick (atomic-free fill), hist fused with gemm1 (block split).
// R5: FAILED - XCD-local workgroup-scope histogram (rank holes -> OOB).
// R6: gather2+gemm2 fusion REGRESSED (355us, occ 25%): 16 rows serialized
//     per wave killed TLP. Lesson: latency-bound gathers need wave count.
// R7 (this round): revert to separate gather2+gemm2 (R2-proven); gathers
//     get an 8-deep software pipeline (batch 8 csr indices, issue 8 row
//     loads before consuming) -> 8 outstanding 256B reads/wave vs 2.
// Pipeline: memset -> gemm1+hist -> scan1 -> scan2 -> scan3+norm ->
//           fill(no atomics) -> gather1 -> gather2 -> gemm2.

// ---------------- fused GEMM1 + edge histogram ----------------
// blocks [0, gemmBlocks): C[M x 64] = A[M x 512] @ B[512 x 64]
// blocks [gemmBlocks, ...): degO[src]++ (float), rank[e] = cnt[dst]++
__launch_bounds__(256)
__global__ void gemm1_hist_kernel(const float* __restrict__ A, const float* __restrict__ B,
                                  float* __restrict__ C, int M,
                                  const int* __restrict__ src, const int* __restrict__ dst,
                                  float* __restrict__ degO, int* __restrict__ cnt,
                                  int* __restrict__ rank, int E, int gemmBlocks) {
    __shared__ __align__(16) float As[32][132];   // k-major, 128 rows + pad
    __shared__ __align__(16) float Bs[32][64];

    if ((int)blockIdx.x >= gemmBlocks) {
        // -------- histogram path (no barriers; device-scope atomics) ------
        int hb = blockIdx.x - gemmBlocks;
        int histThreads = (gridDim.x - gemmBlocks) * 256;
        for (int e = hb * 256 + threadIdx.x; e < E; e += histThreads) {
            int s = src[e];
            int d = dst[e];
            atomicAdd(&degO[s], 1.0f);            // fire-and-forget
            rank[e] = atomicAdd(&cnt[d], 1);      // rank within dst row
        }
        return;
    }

    // -------- gemm path --------
    const int tid = threadIdx.x;
    const int txn = tid & 7;       // 8 col-groups of 8 cols
    const int tym = tid >> 3;      // 32 row-groups of 4 rows
    const int rowBase = blockIdx.x * 128;

    float4 ra[4];  // staged A: 4 x float4 per thread (128x32 tile)
    float4 rb[2];  // staged B: 2 x float4 per thread (32x64 tile)

    auto gload = [&](int k0) {
#pragma unroll
        for (int p = 0; p < 4; ++p) {
            int idx = p * 256 + tid;
            int r  = idx >> 3;
            int kv = (idx & 7) * 4;
            int gr = rowBase + r;
            ra[p] = make_float4(0.f, 0.f, 0.f, 0.f);
            if (gr < M) ra[p] = *(const float4*)(A + (size_t)gr * 512 + k0 + kv);
        }
#pragma unroll
        for (int p = 0; p < 2; ++p) {
            int idx = p * 256 + tid;
            int kr = idx >> 4;
            int nv = (idx & 15) * 4;
            rb[p] = *(const float4*)(B + (size_t)(k0 + kr) * 64 + nv);
        }
    };

    float acc[4][8];
#pragma unroll
    for (int i = 0; i < 4; ++i)
#pragma unroll
        for (int j = 0; j < 8; ++j) acc[i][j] = 0.0f;

    gload(0);
    for (int k0 = 0; k0 < 512; k0 += 32) {
#pragma unroll
        for (int p = 0; p < 4; ++p) {
            int idx = p * 256 + tid;
            int r  = idx >> 3;
            int kv = (idx & 7) * 4;
            As[kv + 0][r] = ra[p].x; As[kv + 1][r] = ra[p].y;
            As[kv + 2][r] = ra[p].z; As[kv + 3][r] = ra[p].w;
        }
#pragma unroll
        for (int p = 0; p < 2; ++p) {
            int idx = p * 256 + tid;
            int kr = idx >> 4;
            int nv = (idx & 15) * 4;
            *(float4*)&Bs[kr][nv] = rb[p];
        }
        __syncthreads();
        if (k0 + 32 < 512) gload(k0 + 32);  // prefetch next tile under compute

#pragma unroll 8
        for (int k = 0; k < 32; ++k) {
            float a[4], b[8];
            *(float4*)&a[0] = *(const float4*)&As[k][tym * 4];
            *(float4*)&b[0] = *(const float4*)&Bs[k][txn * 8];
            *(float4*)&b[4] = *(const float4*)&Bs[k][txn * 8 + 4];
#pragma unroll
            for (int i = 0; i < 4; ++i)
#pragma unroll
                for (int j = 0; j < 8; ++j)
                    acc[i][j] = fmaf(a[i], b[j], acc[i][j]);
        }
        __syncthreads();
    }

#pragma unroll
    for (int i = 0; i < 4; ++i) {
        int gr = rowBase + tym * 4 + i;
        if (gr < M) {
            *(float4*)(C + (size_t)gr * 64 + txn * 8) =
                make_float4(acc[i][0], acc[i][1], acc[i][2], acc[i][3]);
            *(float4*)(C + (size_t)gr * 64 + txn * 8 + 4) =
                make_float4(acc[i][4], acc[i][5], acc[i][6], acc[i][7]);
        }
    }
}

// ---------------- exclusive scan of cnt -> rowptr (3-phase) ----------------
__global__ void scan_pass1(const int* __restrict__ cnt, int* __restrict__ rowptr,
                           int* __restrict__ bsum, int n) {
    __shared__ int tmp[256];
    int tid = threadIdx.x;
    int i = blockIdx.x * 256 + tid;
    int v = (i < n) ? cnt[i] : 0;
    tmp[tid] = v;
    __syncthreads();
    for (int off = 1; off < 256; off <<= 1) {
        int t = (tid >= off) ? tmp[tid - off] : 0;
        __syncthreads();
        tmp[tid] += t;
        __syncthreads();
    }
    if (i < n) rowptr[i] = tmp[tid] - v;  // block-local exclusive
    if (tid == 255) bsum[blockIdx.x] = tmp[255];
}

__global__ void scan_pass2(int* __restrict__ bsum, int nb) {
    __shared__ int tmp[512];
    int tid = threadIdx.x;
    int v = (tid < nb) ? bsum[tid] : 0;
    tmp[tid] = v;
    __syncthreads();
    for (int off = 1; off < 512; off <<= 1) {
        int t = (tid >= off) ? tmp[tid - off] : 0;
        __syncthreads();
        tmp[tid] += t;
        __syncthreads();
    }
    if (tid < nb) bsum[tid] = tmp[tid] - v;  // exclusive block offsets
}

// scan finalize + norm computation fused (ns holds float degO counts)
__global__ void scan3_norm(int* __restrict__ rowptr, const int* __restrict__ bsum,
                           float* __restrict__ ns, float* __restrict__ nd,
                           float* __restrict__ scale2, const int* __restrict__ cnt,
                           int n, int E) {
    int i = blockIdx.x * 256 + threadIdx.x;
    if (i < n) {
        rowptr[i] += bsum[blockIdx.x];
        float a = rsqrtf(fmaxf(ns[i], 1.0f));
        float b = rsqrtf(fmaxf((float)cnt[i], 1.0f));
        ns[i] = a; nd[i] = b; scale2[i] = a * b;
    }
    if (i == 0) rowptr[n] = E;
}

// ---------------- CSR fill: atomic-free via precomputed rank ----------------
__global__ void fill_csr(const int* __restrict__ src, const int* __restrict__ dst,
                         const int* __restrict__ rank, const int* __restrict__ rowptr,
                         int* __restrict__ csr, int E) {
    int e = blockIdx.x * blockDim.x + threadIdx.x;
    if (e < E) {
        csr[rowptr[dst[e]] + rank[e]] = src[e];
    }
}

// ---------------- gather aggregation: one wave per node, lane = feature ----
// 8-deep software pipeline: batch-load 8 csr indices, issue all 8 scale +
// 8 row loads, then consume. 8 outstanding 256B row-reads per wave.
template <bool RELU>
__global__ void gather_kernel(const float* __restrict__ x, const int* __restrict__ rowptr,
                              const int* __restrict__ csr, const float* __restrict__ scale,
                              float* __restrict__ out, int N) {
    int node = blockIdx.x * 4 + (threadIdx.x >> 6);
    if (node >= N) return;
    int lane = threadIdx.x & 63;
    int beg = rowptr[node], end = rowptr[node + 1];
    float acc = 0.0f;
    int i = beg;
    for (; i + 8 <= end; i += 8) {
        int s[8]; float sc[8]; float v[8];
#pragma unroll
        for (int u = 0; u < 8; ++u) s[u] = csr[i + u];
#pragma unroll
        for (int u = 0; u < 8; ++u) {
            sc[u] = scale[s[u]];
            v[u]  = x[(size_t)s[u] * 64 + lane];
        }
#pragma unroll
        for (int u = 0; u < 8; ++u) {
            float t = RELU ? fmaxf(v[u], 0.0f) : v[u];
            acc = fmaf(t, sc[u], acc);
        }
    }
    for (; i + 2 <= end; i += 2) {
        int s0 = csr[i], s1 = csr[i + 1];
        float sc0 = scale[s0], sc1 = scale[s1];
        float v0 = x[(size_t)s0 * 64 + lane];
        float v1 = x[(size_t)s1 * 64 + lane];
        if (RELU) { v0 = fmaxf(v0, 0.0f); v1 = fmaxf(v1, 0.0f); }
        acc = fmaf(v0, sc0, acc);
        acc = fmaf(v1, sc1, acc);
    }
    if (i < end) {
        int s = csr[i];
        float v = x[(size_t)s * 64 + lane];
        if (RELU) v = fmaxf(v, 0.0f);
        acc = fmaf(v, scale[s], acc);
    }
    out[(size_t)node * 64 + lane] = acc;
}

// ---------------- GEMM2: C[M x 512] = (A[M x 64] * nd[row]) @ B[64 x 512] ----------------
__launch_bounds__(256)
__global__ void gemm2_kernel(const float* __restrict__ A, const float* __restrict__ nd,
                             const float* __restrict__ B, float* __restrict__ C, int M) {
    __shared__ __align__(16) float As[64][132];
    __shared__ __align__(16) float Bs[64][132];
    const int tid = threadIdx.x;
    const int txn = tid & 15;
    const int tym = tid >> 4;
    const int rowBase = blockIdx.x * 128;
    const int colBase = blockIdx.y * 128;

#pragma unroll
    for (int p = 0; p < 8; ++p) {
        int idx = p * 256 + tid;
        int r  = idx >> 4;
        int kv = (idx & 15) * 4;
        int gr = rowBase + r;
        float4 v = make_float4(0.f, 0.f, 0.f, 0.f);
        if (gr < M) {
            v = *(const float4*)(A + (size_t)gr * 64 + kv);
            float s = nd[gr];
            v.x *= s; v.y *= s; v.z *= s; v.w *= s;
        }
        As[kv + 0][r] = v.x; As[kv + 1][r] = v.y;
        As[kv + 2][r] = v.z; As[kv + 3][r] = v.w;
    }
#pragma unroll
    for (int p = 0; p < 8; ++p) {
        int idx = p * 256 + tid;
        int kr = idx >> 5;
        int nv = (idx & 31) * 4;
        *(float4*)&Bs[kr][nv] = *(const float4*)(B + (size_t)kr * 512 + colBase + nv);
    }
    __syncthreads();

    float acc[8][8];
#pragma unroll
    for (int i = 0; i < 8; ++i)
#pragma unroll
        for (int j = 0; j < 8; ++j) acc[i][j] = 0.0f;

#pragma unroll 4
    for (int k = 0; k < 64; ++k) {
        float a[8], b[8];
        *(float4*)&a[0] = *(const float4*)&As[k][tym * 8];
        *(float4*)&a[4] = *(const float4*)&As[k][tym * 8 + 4];
        *(float4*)&b[0] = *(const float4*)&Bs[k][txn * 4];
        *(float4*)&b[4] = *(const float4*)&Bs[k][64 + txn * 4];
#pragma unroll
        for (int i = 0; i < 8; ++i)
#pragma unroll
            for (int j = 0; j < 8; ++j)
                acc[i][j] = fmaf(a[i], b[j], acc[i][j]);
    }

#pragma unroll
    for (int i = 0; i < 8; ++i) {
        int gr = rowBase + tym * 8 + i;
        if (gr < M) {
            *(float4*)(C + (size_t)gr * 512 + colBase + txn * 4) =
                make_float4(acc[i][0], acc[i][1], acc[i][2], acc[i][3]);
            *(float4*)(C + (size_t)gr * 512 + colBase + 64 + txn * 4) =
                make_float4(acc[i][4], acc[i][5], acc[i][6], acc[i][7]);
        }
    }
}

extern "C" void kernel_launch(void* const* d_in, const int* in_sizes, int n_in,
                              void* d_out, int out_size, void* d_ws, size_t ws_size,
                              hipStream_t stream) {
    const float* feat = (const float*)d_in[0];
    const int*   src  = (const int*)d_in[1];
    const int*   dst  = (const int*)d_in[2];
    const float* W1   = (const float*)d_in[3];
    const float* W2   = (const float*)d_in[4];
    const int N = in_sizes[0] / 512;  // 100000
    const int E = in_sizes[1];        // 1600000
    float* out = (float*)d_out;

    // workspace layout
    float* ns     = (float*)d_ws;            // [N] (degO counts, then rsqrt)
    float* nd     = ns + N;                  // [N]
    float* scale2 = nd + N;                  // [N] = ns*nd
    int*   cnt    = (int*)(scale2 + N);      // [N] in-degree
    int*   rowptr = cnt + N;                 // [N+1]
    int*   bsum   = rowptr + (N + 1);        // [512]
    int*   csr    = bsum + 512;              // [E]
    float* buf1   = (float*)(((unsigned long long)(csr + E) + 15ull) & ~15ull); // [64N]
    float* agg1   = buf1 + (size_t)64 * N;   // [64N]
    int*   rank   = (int*)agg1;              // [E] aliases agg1 (dead until gather1)

    hipMemsetAsync(ns, 0, (size_t)N * sizeof(float), stream);
    hipMemsetAsync(cnt, 0, (size_t)N * sizeof(int), stream);

    // h1 = feat @ W1, concurrently: degree histograms + rank capture
    const int gemmBlocks = (N + 127) / 128;   // 782
    const int histBlocks = 512;
    gemm1_hist_kernel<<<gemmBlocks + histBlocks, 256, 0, stream>>>(
        feat, W1, buf1, N, src, dst, ns, cnt, rank, E, gemmBlocks);

    const int nb = (N + 255) / 256;  // 391 <= 512
    scan_pass1<<<nb, 256, 0, stream>>>(cnt, rowptr, bsum, N);
    scan_pass2<<<1, 512, 0, stream>>>(bsum, nb);
    scan3_norm<<<nb, 256, 0, stream>>>(rowptr, bsum, ns, nd, scale2, cnt, N, E);

    fill_csr<<<(E + 255) / 256, 256, 0, stream>>>(src, dst, rank, rowptr, csr, E);

    // agg1[d] = sum h1[s]*ns[s]   (rank is dead from here on)
    gather_kernel<false><<<(N + 3) / 4, 256, 0, stream>>>(buf1, rowptr, csr, ns, agg1, N);

    // agg2[d] = sum relu(agg1[s])*ns[s]*nd[s]   (reuse buf1 as agg2)
    gather_kernel<true><<<(N + 3) / 4, 256, 0, stream>>>(agg1, rowptr, csr, scale2, buf1, N);

    // out = (agg2 * nd[row]) @ W2
    gemm2_kernel<<<dim3((N + 127) / 128, 4), 256, 0, stream>>>(buf1, nd, W2, out, N);
}